// Round 5
// baseline (460.387 us; speedup 1.0000x reference)
//
#include <hip/hip_runtime.h>
#include <math.h>

#define NPIX (480*640)
#define MDIM 960
#define MPIX (MDIM*MDIM)

// ws layout (f32 units from base)
#define SCAL_OFF 0        // f32[80]: [0..3] pose-derived, ks at 16/32/48/64 (separate lines)
#define SM_OFF   80       // f32[70000]: 7 planes * 10000
#define VOX0_OFF 70080    // f32[100*100*80]    = 800000   (ch0 voxel grid, [x][y][z])
#define SEM_OFF  870080   // f32[100*100*12*5]  = 300000   (ch1-5, z in [13,25))
// total 1,170,080 f32 = 4.68 MB  (well under prior 11.4 MB usage)

// output layout (floats)
#define OUT_FPMAP 0
#define OUT_MAP   10000
#define OUT_POSE  (10000 + 9*MPIX)

// ---------------- splat: 1200x256, 1 px/thread, direct global-atomic trilinear ----------------
// Fire-and-forget HW fadds (no return -> no waitcnt chain). Corner skipped iff the
// reference's safe mask zeroes it (p>0 && p<dims), numerically identical: reference
// adds weight-0 to a scrambled index in that case. Weight association order matches
// reference: ((wx)*(wy))*(wz).
__global__ __launch_bounds__(256) void splat_kernel(const float* __restrict__ obs,
                                                    float* __restrict__ vox0,
                                                    float* __restrict__ sem5,
                                                    float* __restrict__ scal,
                                                    float fcam) {
    int p = blockIdx.x*256 + threadIdx.x;          // 0..307199
    int i = p / 640, j = p - i*640;
    float d  = obs[3*NPIX + p];
    float f1 = obs[4*NPIX + p];
    float f2 = obs[5*NPIX + p];
    float f3 = obs[6*NPIX + p];
    float f4 = obs[7*NPIX + p];
    float f5 = obs[8*NPIX + p];
    float X = ((float)j - 319.5f) * d / fcam + 250.0f;
    float Z = ((float)(479 - i) - 239.5f) * d / fcam + 88.0f;
    float xs = ((X/5.0f - 50.0f)/100.0f)*2.0f;
    float ys = ((d/5.0f - 50.0f)/100.0f)*2.0f;
    float zs = ((Z/5.0f - 32.0f)/80.0f)*2.0f;
    float pos0 = (xs*100.0f)/2.0f + 50.0f;
    float pos1 = (ys*100.0f)/2.0f + 50.0f;
    float pos2 = (zs*80.0f)/2.0f + 40.0f;
    float fx = floorf(pos0), fy = floorf(pos1), fz = floorf(pos2);
    #pragma unroll
    for (int cx = 0; cx <= 1; cx++) {
        float px = fx + (float)cx;
        if (!(px > 0.0f && px < 100.0f)) continue;
        float wx = 1.0f - fabsf(pos0 - px);
        int ix = (int)px;
        #pragma unroll
        for (int cy = 0; cy <= 1; cy++) {
            float py = fy + (float)cy;
            if (!(py > 0.0f && py < 100.0f)) continue;
            float wy = 1.0f - fabsf(pos1 - py);
            float w01 = wx * wy;                       // reference multiply order
            int col = ix*100 + (int)py;
            #pragma unroll
            for (int cz = 0; cz <= 1; cz++) {
                float pz = fz + (float)cz;
                if (!(pz > 0.0f && pz < 80.0f)) continue;
                float w = w01 * (1.0f - fabsf(pos2 - pz));
                int iz = (int)pz;
                unsafeAtomicAdd(&vox0[col*80 + iz], w);
                if (iz >= 13 && iz < 25) {
                    float* sb = sem5 + (col*12 + (iz - 13))*5;
                    unsafeAtomicAdd(sb + 0, w*f1);
                    unsafeAtomicAdd(sb + 1, w*f2);
                    unsafeAtomicAdd(sb + 2, w*f3);
                    unsafeAtomicAdd(sb + 3, w*f4);
                    unsafeAtomicAdd(sb + 4, w*f5);
                }
            }
        }
    }
    // ks channel maxima (obs values nonnegative), block-level reduce
    float m0 = f1, m1 = f2, m2 = f3, m3 = f4;
    #pragma unroll
    for (int off = 32; off > 0; off >>= 1) {
        m0 = fmaxf(m0, __shfl_down(m0, off, 64));
        m1 = fmaxf(m1, __shfl_down(m1, off, 64));
        m2 = fmaxf(m2, __shfl_down(m2, off, 64));
        m3 = fmaxf(m3, __shfl_down(m3, off, 64));
    }
    __shared__ float red[4][4];
    int lane = threadIdx.x & 63, wave = threadIdx.x >> 6;
    if (lane == 0) {
        red[wave][0] = m0; red[wave][1] = m1; red[wave][2] = m2; red[wave][3] = m3;
    }
    __syncthreads();
    if (threadIdx.x < 4) {
        int c = threadIdx.x;
        float m = fmaxf(fmaxf(red[0][c], red[1][c]), fmaxf(red[2][c], red[3][c]));
        atomicMax((int*)&scal[16*(c+1)], __float_as_int(m));  // slots 16/32/48/64: separate lines
    }
}

// ---------------- reduce: 2500x256, 1 wave = 1 output column; pose fused in block 0 ----------------
// Per-z rintf then column sums: identical math to the reference's round-then-sum.
__global__ __launch_bounds__(256) void reduce_pose_kernel(const float* __restrict__ vox0,
                                                          const float* __restrict__ sem5,
                                                          float* __restrict__ sm,
                                                          float* __restrict__ out_fp,
                                                          const float* pose_obs,
                                                          const float* poses_last,
                                                          float* scal, float* out_pose) {
    if (blockIdx.x == 0 && threadIdx.x == 0) {
        const float DEGc = 57.29577951308232f;
        float th = poses_last[2] / DEGc;
        float s = sinf(th), c = cosf(th);
        float ny = poses_last[1] + pose_obs[0]*s + pose_obs[1]*c;
        float nx = poses_last[0] + pose_obs[0]*c - pose_obs[1]*s;
        float nt = poses_last[2] + pose_obs[2]*DEGc;
        nt = fmodf(nt - 180.0f, 360.0f) + 180.0f;
        nt = fmodf(nt + 180.0f, 360.0f) - 180.0f;
        out_pose[0] = nx; out_pose[1] = ny; out_pose[2] = nt;
        out_pose[3] = nx; out_pose[4] = ny; out_pose[5] = nt;
        float sx = -((nx*100.0f)/5.0f - 480.0f)/480.0f;
        float sy = -((ny*100.0f)/5.0f - 480.0f)/480.0f;
        float sth = ((90.0f - nt) * 3.14159265358979323846f) / 180.0f;
        scal[0] = cosf(sth);
        scal[1] = sinf(sth);
        scal[2] = sx;
        scal[3] = sy;
    }
    int wave = threadIdx.x >> 6, lane = threadIdx.x & 63;
    int t = blockIdx.x*4 + wave;       // 2500*4 = 10000 exactly; t = y*100+x (row-major y,x)
    int x = t % 100, y = t / 100;
    int col = x*100 + y;               // voxel grid is [x][y][z]
    const float* vz = vox0 + col*80;
    int z = lane;                      // z in [0,64); [64,80) folded by lanes 0..15
    float r0 = rintf(vz[z]);
    float all0 = r0;
    if (lane < 16) all0 += rintf(vz[64 + z]);
    bool inb = (z >= 13 && z < 25);
    float a0 = inb ? r0 : 0.0f;
    float a1 = 0.f, a2 = 0.f, a3 = 0.f, a4 = 0.f, a5 = 0.f;
    if (inb) {
        const float* sb = sem5 + (col*12 + (z - 13))*5;
        a1 = rintf(sb[0]);
        a2 = rintf(sb[1]);
        a3 = rintf(sb[2]);
        a4 = rintf(sb[3]);
        a5 = rintf(sb[4]);
    }
    #pragma unroll
    for (int off = 32; off > 0; off >>= 1) {
        all0 += __shfl_down(all0, off, 64);
        a0 += __shfl_down(a0, off, 64);
        a1 += __shfl_down(a1, off, 64);
        a2 += __shfl_down(a2, off, 64);
        a3 += __shfl_down(a3, off, 64);
        a4 += __shfl_down(a4, off, 64);
        a5 += __shfl_down(a5, off, 64);
    }
    if (lane == 0) {
        float fp = fminf(a0, 1.0f);
        float ex = fminf(all0, 1.0f);
        sm[0*10000 + t] = fp;
        sm[1*10000 + t] = ex;
        sm[2*10000 + t] = fminf(a1/5.0f, 1.0f);
        sm[3*10000 + t] = fminf(a2/5.0f, 1.0f);
        sm[4*10000 + t] = fminf(a3/5.0f, 1.0f);
        sm[5*10000 + t] = fminf(a4/5.0f, 1.0f);
        sm[6*10000 + t] = fminf(a5/5.0f, 1.0f);
        out_fp[t] = fp;
    }
}

// bilinear sample of the (implicit, mostly-zero) agent_view at normalized coords
__device__ __forceinline__ void sample_agent(float gxv, float gyv,
                                             float ct, float sn,
                                             const float* __restrict__ sm,
                                             float rot[7]) {
    float u = ct*gxv - sn*gyv;
    float v = sn*gxv + ct*gyv;
    float xim = ((u + 1.0f)*0.5f)*959.0f;
    float yim = ((v + 1.0f)*0.5f)*959.0f;
    float x0 = floorf(xim), y0 = floorf(yim);
    #pragma unroll
    for (int ty = 0; ty <= 1; ty++) {
        float yy = y0 + (float)ty;
        if (yy < 480.0f || yy >= 580.0f) continue;   // region rows [480,580)
        float wy = 1.0f - fabsf(yim - yy);
        int yi = (int)yy - 480;
        #pragma unroll
        for (int tx = 0; tx <= 1; tx++) {
            float xx = x0 + (float)tx;
            if (xx < 430.0f || xx >= 530.0f) continue;  // region cols [430,530)
            float w = (1.0f - fabsf(xim - xx)) * wy;
            int o = yi*100 + ((int)xx - 430);
            #pragma unroll
            for (int k = 0; k < 7; k++) rot[k] += sm[k*10000 + o] * w;
        }
    }
}

__device__ __forceinline__ void pixel_ts(float xim, float yim, float ct, float sn,
                                         const float* __restrict__ sm, float ts[7]) {
    const float step = 2.0f/959.0f;
    float x0 = floorf(xim), y0 = floorf(yim);
    #pragma unroll
    for (int ty = 0; ty <= 1; ty++) {
        float yy = y0 + (float)ty;
        if (yy < 0.0f || yy > 959.0f) continue;
        float wy = 1.0f - fabsf(yim - yy);
        #pragma unroll
        for (int tx = 0; tx <= 1; tx++) {
            float xx = x0 + (float)tx;
            if (xx < 0.0f || xx > 959.0f) continue;
            float w = (1.0f - fabsf(xim - xx)) * wy;
            float rot[7] = {0,0,0,0,0,0,0};
            float gx1 = xx*step - 1.0f;
            float gy1 = yy*step - 1.0f;
            sample_agent(gx1, gy1, ct, sn, sm, rot);
            #pragma unroll
            for (int k = 0; k < 7; k++) ts[k] += rot[k]*w;
        }
    }
}

// ---------------- final: 4 px/thread, float4 fast path ----------------
__global__ __launch_bounds__(256) void final_kernel(const float* __restrict__ maps_last,
                                                    const float* __restrict__ sm,
                                                    const float* __restrict__ scal,
                                                    float* __restrict__ out_map) {
    int g = blockIdx.x*256 + threadIdx.x;    // 0..230399
    int p = g*4;
    int y = p / MDIM, xp = p - y*MDIM;       // 4 pixels share a row (960%4==0)
    float ct = scal[0], sn = scal[1], sx = scal[2], sy = scal[3];
    const float step = 2.0f/959.0f;
    float gyv = (float)y*step - 1.0f;
    float v = gyv + sy;
    float yim = ((v + 1.0f)*0.5f)*959.0f;
    float gyc = yim*step - 1.0f;
    float xims[4];
    bool act[4];
    bool any = false;
    #pragma unroll
    for (int q = 0; q < 4; q++) {
        float gxv = (float)(xp+q)*step - 1.0f;
        float u = gxv + sx;
        float xim = ((u + 1.0f)*0.5f)*959.0f;
        xims[q] = xim;
        // Early reject: rotation is an isometry; the 4 translation taps lie
        // within sqrt(2) px of the rotated center; >1.5 px outside the active
        // window (rows (479,580), cols (429,530)) -> every sample exactly 0.
        float gxc = xim*step - 1.0f;
        float uc = ct*gxc - sn*gyc;
        float vc = sn*gxc + ct*gyc;
        float xc2 = ((uc + 1.0f)*0.5f)*959.0f;
        float yc2 = ((vc + 1.0f)*0.5f)*959.0f;
        bool a = (xc2 > 427.5f) && (xc2 < 531.5f) && (yc2 > 477.5f) && (yc2 < 581.5f);
        act[q] = a;
        any = any || a;
    }
    if (!any) {
        // ts == 0 exactly for all 4 pixels: every channel -> max(ml, 0)
        #pragma unroll
        for (int c = 0; c < 9; c++) {
            float4 ml = *(const float4*)(maps_last + c*MPIX + p);
            float4 o;
            o.x = fmaxf(ml.x, 0.0f); o.y = fmaxf(ml.y, 0.0f);
            o.z = fmaxf(ml.z, 0.0f); o.w = fmaxf(ml.w, 0.0f);
            *(float4*)(out_map + c*MPIX + p) = o;
        }
        return;
    }
    float ks0 = scal[16], ks1 = scal[32], ks2 = scal[48], ks3 = scal[64];
    #pragma unroll
    for (int q = 0; q < 4; q++) {
        int o = p + q;
        float ts[7] = {0,0,0,0,0,0,0};
        if (act[q]) pixel_ts(xims[q], yim, ct, sn, sm, ts);
        float ml;
        ml = maps_last[0*MPIX + o]; out_map[0*MPIX + o] = fmaxf(ml, ts[0]);
        ml = maps_last[1*MPIX + o]; out_map[1*MPIX + o] = fmaxf(ml, ts[1]);
        ml = maps_last[2*MPIX + o]; out_map[2*MPIX + o] = fmaxf(ml, 0.0f);
        ml = maps_last[3*MPIX + o]; out_map[3*MPIX + o] = fmaxf(ml, 0.0f);
        float t4 = ts[2]; t4 = (t4 > 0.0f) ? ks0 : t4;
        ml = maps_last[4*MPIX + o]; out_map[4*MPIX + o] = fmaxf(ml, t4);
        float t5 = ts[3]; t5 = (t5 > 0.0f) ? ks1 : t5;
        ml = maps_last[5*MPIX + o]; out_map[5*MPIX + o] = fmaxf(ml, t5);
        float t6 = ts[4]; t6 = (t6 > 0.0f) ? ks2 : t6;
        ml = maps_last[6*MPIX + o]; out_map[6*MPIX + o] = fmaxf(ml, t6);
        float t7 = ts[5]; t7 = (t7 > 0.0f) ? ks3 : t7;
        ml = maps_last[7*MPIX + o]; out_map[7*MPIX + o] = fmaxf(ml, t7);
        ml = maps_last[8*MPIX + o]; out_map[8*MPIX + o] = fmaxf(ml, ts[6]);
    }
}

extern "C" void kernel_launch(void* const* d_in, const int* in_sizes, int n_in,
                              void* d_out, int out_size, void* d_ws, size_t ws_size,
                              hipStream_t stream) {
    const float* obs        = (const float*)d_in[0];
    const float* pose_obs   = (const float*)d_in[1];
    const float* maps_last  = (const float*)d_in[2];
    const float* poses_last = (const float*)d_in[3];
    float* out = (float*)d_out;

    float* ws_f = (float*)d_ws;
    float* scal = ws_f + SCAL_OFF;
    float* sm   = ws_f + SM_OFF;
    float* vox0 = ws_f + VOX0_OFF;
    float* sem5 = ws_f + SEM_OFF;

    // zero scal (320B) + voxel grids (4.4MB); ws is poisoned 0xAA each launch
    hipMemsetAsync(scal, 0, 80u * 4u, stream);
    hipMemsetAsync(vox0, 0, (size_t)(800000 + 300000) * 4u, stream);

    float fcam = (float)(320.0 / tan(39.5 * M_PI / 180.0));

    splat_kernel<<<1200, 256, 0, stream>>>(obs, vox0, sem5, scal, fcam);
    reduce_pose_kernel<<<2500, 256, 0, stream>>>(vox0, sem5, sm, out + OUT_FPMAP,
                                                 pose_obs, poses_last,
                                                 scal, out + OUT_POSE);
    final_kernel<<<900, 256, 0, stream>>>(maps_last, sm, scal, out + OUT_MAP);
}